// Round 3
// baseline (617.855 us; speedup 1.0000x reference)
//
#include <hip/hip_runtime.h>
#include <cmath>

// ROIAlignV2 multi-level FPN pooler, LDS-staged windows. fp32 in/out.
constexpr int OUTD = 14;
constexpr int NBIN = OUTD * OUTD;   // 196
constexpr int NS   = 28;            // OUT*SR samples per axis
constexpr int CTOT = 256;           // total channels
constexpr int QC   = 64;            // channels per block (quarter)
constexpr int G    = 4;             // channels staged per round
constexpr int SLOT = 1536;          // floats per channel window slot (worst ~1120)
constexpr int NT   = 256;           // threads per block
constexpr int NW   = NT / 64;       // waves per block

__global__ __launch_bounds__(NT) void roi_pool_kernel(
    const float* __restrict__ f0, const float* __restrict__ f1,
    const float* __restrict__ f2, const float* __restrict__ f3,
    const float* __restrict__ boxes, const int* __restrict__ bidx,
    float* __restrict__ out)
{
    const int m = blockIdx.x;   // box
    const int q = blockIdx.y;   // channel quarter (0..3)

    // ---- box-uniform parameters ----
    const float bx0 = boxes[m*4+0], by0 = boxes[m*4+1];
    const float bx1 = boxes[m*4+2], by1 = boxes[m*4+3];
    const float size = sqrtf((bx1 - bx0) * (by1 - by0));
    float lf = floorf(4.0f + log2f(size / 224.0f + 2.220446049250313e-16f));
    lf = fminf(fmaxf(lf, 2.0f), 5.0f);
    const int L = (int)lf - 2;                       // 0..3
    const float scale = (L == 0) ? 0.25f  : (L == 1) ? 0.125f
                       : (L == 2) ? 0.0625f : 0.03125f;
    const int HW = 256 >> L;                         // square feature map
    const float* feat = (L == 0) ? f0 : (L == 1) ? f1 : (L == 2) ? f2 : f3;
    const int b = bidx[m];

    // ---- per-sample tables (window-relative), packed {lo,hi,wl,wh} ----
    __shared__ int4  s_tab[2][NS];          // axis 0 = x, axis 1 = y
    __shared__ int   s_x0, s_y0, s_ww, s_wh;
    __shared__ float s_win[G * SLOT];

    const int t = threadIdx.x;
    if (t < 2 * NS) {
        const int axis = t / NS;            // 0 = x, 1 = y
        const int s    = t % NS;
        const float c0 = (axis ? by0 : bx0) * scale - 0.5f;
        const float c1 = (axis ? by1 : bx1) * scale - 0.5f;
        const float binw = (c1 - c0) * (1.0f / OUTD);
        const float g = (float)(s >> 1) + ((s & 1) ? 0.75f : 0.25f);
        const float p = c0 + g * binw;
        const bool valid = (p > -1.0f) && (p < (float)HW);
        const float pc = fminf(fmaxf(p, 0.0f), (float)(HW - 1));
        const int lo = (int)floorf(pc);
        const int hi = min(lo + 1, HW - 1);
        const float l = pc - (float)lo;
        // window origin for this axis = lo of sample 0 (monotonic in s)
        const float p0  = c0 + 0.25f * binw;
        const float pc0 = fminf(fmaxf(p0, 0.0f), (float)(HW - 1));
        const int   lo0 = (int)floorf(pc0);
        int4 e;
        e.x = lo - lo0;
        e.y = hi - lo0;
        e.z = __float_as_int(valid ? (1.0f - l) : 0.0f);
        e.w = __float_as_int(valid ? l : 0.0f);
        s_tab[axis][s] = e;
        if (s == NS - 1) {                  // window extent from last sample's hi
            if (axis == 0) { s_x0 = lo0; s_ww = hi - lo0 + 1; }
            else           { s_y0 = lo0; s_wh = hi - lo0 + 1; }
        }
    }
    __syncthreads();

    const int x0 = s_x0, y0 = s_y0, ww = s_ww, wh = s_wh;
    const int wwp = ww | 1;                 // odd stride -> per-row bank rotation
    const int wave = t >> 6, lane = t & 63;
    const size_t chan_stride = (size_t)HW * HW;
    const float* gq = feat + ((size_t)(b * CTOT) + q * QC) * chan_stride;

    for (int r = 0; r < QC / G; ++r) {      // 16 rounds of G=4 channels
        // ---- stage G channel windows (coalesced row segments) ----
        #pragma unroll
        for (int c = 0; c < G; ++c) {
            const float* gc = gq + (size_t)(r * G + c) * chan_stride
                            + (size_t)y0 * HW + x0;
            float* lc = s_win + c * SLOT;
            for (int ry = wave; ry < wh; ry += NW) {
                const float* grow = gc + (size_t)ry * HW;
                float* lrow = lc + ry * wwp;
                for (int rx = lane; rx < ww; rx += 64)
                    lrow[rx] = grow[rx];
            }
        }
        __syncthreads();

        // ---- compute G*196 outputs from LDS ----
        for (int o = t; o < G * NBIN; o += NT) {
            const int cl  = o / NBIN;
            const int bin = o - cl * NBIN;
            const int ph  = bin / OUTD;
            const int pw  = bin - ph * OUTD;

            const int4 ty0 = s_tab[1][2*ph], ty1 = s_tab[1][2*ph+1];
            const int4 tx0 = s_tab[0][2*pw], tx1 = s_tab[0][2*pw+1];

            int ro[4]; float wy[4];
            ro[0] = ty0.x * wwp; wy[0] = __int_as_float(ty0.z);
            ro[1] = ty0.y * wwp; wy[1] = __int_as_float(ty0.w);
            ro[2] = ty1.x * wwp; wy[2] = __int_as_float(ty1.z);
            ro[3] = ty1.y * wwp; wy[3] = __int_as_float(ty1.w);
            int co[4]; float wx[4];
            co[0] = tx0.x; wx[0] = __int_as_float(tx0.z);
            co[1] = tx0.y; wx[1] = __int_as_float(tx0.w);
            co[2] = tx1.x; wx[2] = __int_as_float(tx1.z);
            co[3] = tx1.y; wx[3] = __int_as_float(tx1.w);

            const float* lb = s_win + cl * SLOT;
            float acc = 0.0f;
            #pragma unroll
            for (int k = 0; k < 16; ++k)
                acc += (wy[k >> 2] * wx[k & 3]) * lb[ro[k >> 2] + co[k & 3]];

            const int ch = q * QC + r * G + cl;
            out[((size_t)m * CTOT + ch) * NBIN + bin] = acc * 0.25f;
        }
        __syncthreads();
    }
}

extern "C" void kernel_launch(void* const* d_in, const int* in_sizes, int n_in,
                              void* d_out, int out_size, void* d_ws, size_t ws_size,
                              hipStream_t stream) {
    const float* f0    = (const float*)d_in[0];
    const float* f1    = (const float*)d_in[1];
    const float* f2    = (const float*)d_in[2];
    const float* f3    = (const float*)d_in[3];
    const float* boxes = (const float*)d_in[4];
    const int*   bidx  = (const int*)d_in[5];
    float* out = (float*)d_out;

    const int M = in_sizes[5];           // number of boxes
    dim3 grid(M, CTOT / QC);             // (256, 4)
    roi_pool_kernel<<<grid, NT, 0, stream>>>(f0, f1, f2, f3, boxes, bidx, out);
}

// Round 4
// 274.043 us; speedup vs baseline: 2.2546x; 2.2546x over previous
//
#include <hip/hip_runtime.h>
#include <cmath>
#include <type_traits>

// ROIAlignV2 multi-level FPN pooler. fp32 in/out.
// Strategy: 2-pass. S: NCHW window -> NHWC workspace (all accesses coalesced).
//           P: gather taps with lanes-over-channels (1KB contiguous loads).
constexpr int OUTD = 14;
constexpr int NBIN = OUTD * OUTD;   // 196
constexpr int NS   = 28;            // samples per axis
constexpr int CTOT = 256;           // channels
constexpr int SLOT_PX = 1024;       // px slots per box (worst-case window ~992)
constexpr int TILE_W  = 133;        // odd -> conflict-free column reads

// ---- shared box/window math (must be bit-identical in S and P) ----
__device__ inline void box_params(const float* __restrict__ boxes,
                                  const int* __restrict__ bidx, int m,
                                  const float* f0, const float* f1,
                                  const float* f2, const float* f3,
                                  int& b, int& HW, float& scale,
                                  const float*& feat,
                                  float& bx0, float& by0, float& bx1, float& by1)
{
    bx0 = boxes[m*4+0]; by0 = boxes[m*4+1];
    bx1 = boxes[m*4+2]; by1 = boxes[m*4+3];
    const float size = sqrtf((bx1-bx0)*(by1-by0));
    float lf = floorf(4.0f + log2f(size/224.0f + 2.220446049250313e-16f));
    lf = fminf(fmaxf(lf, 2.0f), 5.0f);
    const int L = (int)lf - 2;
    scale = (L==0)?0.25f:(L==1)?0.125f:(L==2)?0.0625f:0.03125f;
    HW = 256 >> L;
    feat = (L==0)?f0:(L==1)?f1:(L==2)?f2:f3;
    b = bidx[m];
}

__device__ inline void axis_window(float c0, float c1, int HW, int& lo0, int& ext)
{
    const float binw = (c1 - c0) * (1.0f/OUTD);
    const float HWm1 = (float)(HW-1);
    const float pL = fminf(fmaxf(c0 + 0.25f*binw, 0.f), HWm1);   // sample 0
    const float pH = fminf(fmaxf(c0 + 13.75f*binw, 0.f), HWm1);  // sample 27
    const int loL = (int)floorf(pL);
    const int loH = (int)floorf(pH);
    const int hiH = min(loH + 1, HW - 1);
    lo0 = loL;
    ext = hiH - loL + 1;
}

// ---- Pass S: stage window, NCHW -> [m][px][CH_R] ----
template<int CH_R>
__global__ __launch_bounds__(256) void stage_kernel(
    const float* __restrict__ f0, const float* __restrict__ f1,
    const float* __restrict__ f2, const float* __restrict__ f3,
    const float* __restrict__ boxes, const int* __restrict__ bidx,
    float* __restrict__ ws, int cg0)
{
    const int m  = blockIdx.x;
    const int cg = blockIdx.y;            // 64-ch subgroup within CH_R
    int b, HW; float scale; const float* feat;
    float bx0, by0, bx1, by1;
    box_params(boxes, bidx, m, f0, f1, f2, f3, b, HW, scale, feat, bx0, by0, bx1, by1);
    int x0, ww, y0, wh;
    axis_window(bx0*scale - 0.5f, bx1*scale - 0.5f, HW, x0, ww);
    axis_window(by0*scale - 0.5f, by1*scale - 0.5f, HW, y0, wh);
    ww = min(ww, TILE_W);                       // never triggers (ww<=126)
    if (ww*wh > SLOT_PX) wh = SLOT_PX / ww;     // never triggers (safety)

    __shared__ float s_tile[64 * TILE_W];
    __shared__ int   s_goff[TILE_W];

    const int t = threadIdx.x, wave = t >> 6, lane = t & 63;
    const int R = min(TILE_W / ww, wh);         // rows per chunk
    if (t < R*ww) { const int r = t / ww; s_goff[t] = r*HW + (t - r*ww); }
    __syncthreads();

    const float* gch = feat + ((size_t)(b*CTOT + cg0 + cg*64))*HW*HW
                     + (size_t)y0*HW + x0;
    float* wsm = ws + (size_t)m * SLOT_PX * CH_R + cg*64;

    for (int y = 0; y < wh; y += R) {
        const int rows  = min(R, wh - y);
        const int chunk = rows * ww;
        // A: global rows -> LDS tile [cl][e]
        for (int cl = wave; cl < 64; cl += 4) {
            const float* g = gch + (size_t)cl*HW*HW + (size_t)y*HW;
            float* tl = s_tile + cl*TILE_W;
            for (int e = lane; e < chunk; e += 64)
                tl[e] = g[s_goff[e]];
        }
        __syncthreads();
        // B: LDS tile -> ws (channel-contiguous)
        const int nel = chunk << 6;
        for (int k = t; k < nel; k += 256) {
            const int e = k >> 6, cl = k & 63;
            wsm[(size_t)(y*ww + e)*CH_R + cl] = s_tile[cl*TILE_W + e];
        }
        __syncthreads();
    }
}

// ---- small vector helpers ----
__device__ inline void vzero(float4& a){ a.x=a.y=a.z=a.w=0.f; }
__device__ inline void vzero(float& a){ a=0.f; }
__device__ inline void axpy(float4& a, float w, const float4& v){
    a.x=fmaf(w,v.x,a.x); a.y=fmaf(w,v.y,a.y); a.z=fmaf(w,v.z,a.z); a.w=fmaf(w,v.w,a.w); }
__device__ inline void axpy(float& a, float w, const float& v){ a=fmaf(w,v,a); }
__device__ inline void vadd(float4& a, const float4& b){ a.x+=b.x; a.y+=b.y; a.z+=b.z; a.w+=b.w; }
__device__ inline void vadd(float& a, const float& b){ a+=b; }
__device__ inline void vscale(float4& a, float s){ a.x*=s; a.y*=s; a.z*=s; a.w*=s; }
__device__ inline void vscale(float& a, float s){ a*=s; }
__device__ inline void ldv(float4& d, const float* p, int lane){ d = ((const float4*)p)[lane]; }
__device__ inline void ldv(float& d, const float* p, int lane){ d = p[lane]; }
__device__ inline void obw(float* ob, int lane, const float4& a){
    ob[4*lane]=a.x; ob[4*lane+1]=a.y; ob[4*lane+2]=a.z; ob[4*lane+3]=a.w; }
__device__ inline void obw(float* ob, int lane, const float& a){ ob[lane]=a; }

// ---- Pass P: sample from [m][px][CH_R], lanes over channels ----
template<int CH_R>
__global__ __launch_bounds__(256) void pool_kernel(
    const float* __restrict__ f0, const float* __restrict__ f1,
    const float* __restrict__ f2, const float* __restrict__ f3,
    const float* __restrict__ boxes, const int* __restrict__ bidx,
    const float* __restrict__ ws, float* __restrict__ out, int cg0)
{
    using AccT = std::conditional_t<CH_R==256, float4, float>;
    const int m  = blockIdx.x;
    const int bb = blockIdx.y;            // 0..6 -> bins [28bb, 28bb+28)
    int b, HW; float scale; const float* feat;
    float bx0, by0, bx1, by1;
    box_params(boxes, bidx, m, f0, f1, f2, f3, b, HW, scale, feat, bx0, by0, bx1, by1);
    int x0, ww, y0, wh;
    axis_window(bx0*scale - 0.5f, bx1*scale - 0.5f, HW, x0, ww);
    axis_window(by0*scale - 0.5f, by1*scale - 0.5f, HW, y0, wh);
    ww = min(ww, TILE_W);

    __shared__ int4  s_tab[2][NS];
    __shared__ float obuf[28 * (CH_R + 1)];

    const int t = threadIdx.x, wave = t >> 6, lane = t & 63;
    if (t < 2*NS) {
        const int axis = t / NS, s = t % NS;
        const float c0 = (axis ? by0 : bx0) * scale - 0.5f;
        const float c1 = (axis ? by1 : bx1) * scale - 0.5f;
        const float binw = (c1 - c0) * (1.0f/OUTD);
        const float g = (float)(s >> 1) + ((s & 1) ? 0.75f : 0.25f);
        const float p = c0 + g * binw;
        const bool valid = (p > -1.0f) && (p < (float)HW);
        const float pc = fminf(fmaxf(p, 0.0f), (float)(HW - 1));
        const int lo = (int)floorf(pc);
        const int hi = min(lo + 1, HW - 1);
        const float l = pc - (float)lo;
        int lo0, ext;
        axis_window(c0, c1, HW, lo0, ext);
        int4 e;
        e.x = lo - lo0; e.y = hi - lo0;
        e.z = __float_as_int(valid ? (1.0f - l) : 0.0f);
        e.w = __float_as_int(valid ? l : 0.0f);
        s_tab[axis][s] = e;
    }
    __syncthreads();

    const float* mbase = ws + (size_t)m * SLOT_PX * CH_R;

    for (int lb = 7*wave; lb < 7*wave + 7; ++lb) {
        const int bin = 28*bb + lb;
        const int ph = bin / OUTD, pw = bin - ph*OUTD;
        const int4 ty0 = s_tab[1][2*ph], ty1 = s_tab[1][2*ph+1];
        const int4 tx0 = s_tab[0][2*pw], tx1 = s_tab[0][2*pw+1];
        int ro[4]; float wy[4];
        ro[0]=ty0.x*ww; wy[0]=__int_as_float(ty0.z);
        ro[1]=ty0.y*ww; wy[1]=__int_as_float(ty0.w);
        ro[2]=ty1.x*ww; wy[2]=__int_as_float(ty1.z);
        ro[3]=ty1.y*ww; wy[3]=__int_as_float(ty1.w);
        int co[4]; float wx[4];
        co[0]=tx0.x; wx[0]=__int_as_float(tx0.z);
        co[1]=tx0.y; wx[1]=__int_as_float(tx0.w);
        co[2]=tx1.x; wx[2]=__int_as_float(tx1.z);
        co[3]=tx1.y; wx[3]=__int_as_float(tx1.w);

        AccT v[16]; float wt[16];
        #pragma unroll
        for (int k = 0; k < 16; ++k) {
            const int px = min(ro[k>>2] + co[k&3], SLOT_PX - 1);
            ldv(v[k], mbase + (size_t)px * CH_R, lane);
            wt[k] = wy[k>>2] * wx[k&3];
        }
        AccT a0, a1, a2, a3; vzero(a0); vzero(a1); vzero(a2); vzero(a3);
        #pragma unroll
        for (int k = 0; k < 16; k += 4) {
            axpy(a0, wt[k],   v[k]);
            axpy(a1, wt[k+1], v[k+1]);
            axpy(a2, wt[k+2], v[k+2]);
            axpy(a3, wt[k+3], v[k+3]);
        }
        vadd(a0, a1); vadd(a2, a3); vadd(a0, a2); vscale(a0, 0.25f);
        obw(obuf + lb*(CH_R+1), lane, a0);
    }
    __syncthreads();

    // obuf [28][CH_R] -> out [c][bin], bin-contiguous stores
    for (int s = t; s < 28*CH_R; s += 256) {
        const int c = s / 28, bp = s - 28*c;
        out[((size_t)(m*CTOT + cg0 + c))*NBIN + 28*bb + bp] = obuf[bp*(CH_R+1) + c];
    }
}

// ---- fallback: R2 direct-gather (used when ws is too small) ----
__global__ __launch_bounds__(256) void roi_pool_direct(
    const float* __restrict__ f0, const float* __restrict__ f1,
    const float* __restrict__ f2, const float* __restrict__ f3,
    const float* __restrict__ boxes, const int* __restrict__ bidx,
    float* __restrict__ out)
{
    const int m  = blockIdx.x;
    const int cg = blockIdx.y;
    int b, HW; float scale; const float* feat;
    float bx0, by0, bx1, by1;
    box_params(boxes, bidx, m, f0, f1, f2, f3, b, HW, scale, feat, bx0, by0, bx1, by1);

    __shared__ int4 s_tab[2][NS];
    const int t = threadIdx.x;
    if (t < 2*NS) {
        const int axis = t / NS, s = t % NS;
        const float c0 = (axis ? by0 : bx0) * scale - 0.5f;
        const float c1 = (axis ? by1 : bx1) * scale - 0.5f;
        const float binw = (c1 - c0) * (1.0f/OUTD);
        const float g = (float)(s >> 1) + ((s & 1) ? 0.75f : 0.25f);
        const float p = c0 + g * binw;
        const bool valid = (p > -1.0f) && (p < (float)HW);
        const float pc = fminf(fmaxf(p, 0.0f), (float)(HW - 1));
        const int lo = (int)floorf(pc);
        const int hi = min(lo + 1, HW - 1);
        const float l = pc - (float)lo;
        int4 e; e.x = lo; e.y = hi;
        e.z = __float_as_int(valid ? (1.0f - l) : 0.0f);
        e.w = __float_as_int(valid ? l : 0.0f);
        s_tab[axis][s] = e;
    }
    __syncthreads();

    const int W = HW;
    const size_t cs = (size_t)HW*HW;
    const float* gbase = feat + (size_t)(b*CTOT + cg*32)*cs;
    for (int i = t; i < 16*NBIN; i += 256) {
        const int cl = i / NBIN, bin = i - cl*NBIN;
        const int ph = bin / OUTD, pw = bin - ph*OUTD;
        const int4 ty0 = s_tab[1][2*ph], ty1 = s_tab[1][2*ph+1];
        const int4 tx0 = s_tab[0][2*pw], tx1 = s_tab[0][2*pw+1];
        int rs[4]; float wy[4];
        rs[0]=ty0.x*W; wy[0]=__int_as_float(ty0.z);
        rs[1]=ty0.y*W; wy[1]=__int_as_float(ty0.w);
        rs[2]=ty1.x*W; wy[2]=__int_as_float(ty1.z);
        rs[3]=ty1.y*W; wy[3]=__int_as_float(ty1.w);
        int cx[4]; float wx[4];
        cx[0]=tx0.x; wx[0]=__int_as_float(tx0.z);
        cx[1]=tx0.y; wx[1]=__int_as_float(tx0.w);
        cx[2]=tx1.x; wx[2]=__int_as_float(tx1.z);
        cx[3]=tx1.y; wx[3]=__int_as_float(tx1.w);
        const float* b0 = gbase + (size_t)cl*cs;
        const float* b1 = b0 + (size_t)16*cs;
        float v0[16], v1[16], w[16];
        #pragma unroll
        for (int k = 0; k < 16; ++k) {
            const int off = rs[k>>2] + cx[k&3];
            v0[k] = b0[off]; v1[k] = b1[off];
            w[k] = wy[k>>2]*wx[k&3];
        }
        float A0=0.f, A1=0.f;
        #pragma unroll
        for (int k = 0; k < 16; ++k) { A0 += w[k]*v0[k]; A1 += w[k]*v1[k]; }
        const size_t ob = ((size_t)m*CTOT + cg*32 + cl)*NBIN + bin;
        out[ob] = A0*0.25f;
        out[ob + (size_t)16*NBIN] = A1*0.25f;
    }
}

extern "C" void kernel_launch(void* const* d_in, const int* in_sizes, int n_in,
                              void* d_out, int out_size, void* d_ws, size_t ws_size,
                              hipStream_t stream) {
    const float* f0    = (const float*)d_in[0];
    const float* f1    = (const float*)d_in[1];
    const float* f2    = (const float*)d_in[2];
    const float* f3    = (const float*)d_in[3];
    const float* boxes = (const float*)d_in[4];
    const int*   bidx  = (const int*)d_in[5];
    float* out = (float*)d_out;
    float* ws  = (float*)d_ws;

    const int M = in_sizes[5];
    const size_t need256 = (size_t)M * SLOT_PX * 256 * sizeof(float);
    const size_t need64  = (size_t)M * SLOT_PX * 64  * sizeof(float);

    if (ws_size >= need256) {
        stage_kernel<256><<<dim3(M,4), 256, 0, stream>>>(f0,f1,f2,f3,boxes,bidx,ws,0);
        pool_kernel<256><<<dim3(M,7), 256, 0, stream>>>(f0,f1,f2,f3,boxes,bidx,ws,out,0);
    } else if (ws_size >= need64) {
        for (int r = 0; r < 4; ++r) {
            stage_kernel<64><<<dim3(M,1), 256, 0, stream>>>(f0,f1,f2,f3,boxes,bidx,ws,64*r);
            pool_kernel<64><<<dim3(M,7), 256, 0, stream>>>(f0,f1,f2,f3,boxes,bidx,ws,out,64*r);
        }
    } else {
        roi_pool_direct<<<dim3(M,8), 256, 0, stream>>>(f0,f1,f2,f3,boxes,bidx,out);
    }
}

// Round 5
// 166.164 us; speedup vs baseline: 3.7184x; 1.6492x over previous
//
#include <hip/hip_runtime.h>
#include <cmath>

// ROIAlignV2 multi-level FPN pooler. fp32 in/out.
// R5: dense NCHW->NHWC transpose of levels 1-3 only (44MB) + coalesced NHWC
// pool for L1-3 boxes; direct gather for L0 boxes (small minority).
constexpr int OUTD = 14;
constexpr int NBIN = OUTD * OUTD;   // 196
constexpr int NS   = 28;            // samples per axis
constexpr int CTOT = 256;           // channels

// ws layout (floats): lvl1 [2][16384][256] @ OFF1, lvl2 [2][4096][256] @ OFF2,
//                     lvl3 [2][1024][256] @ OFF3
constexpr size_t OFF1 = 0;
constexpr size_t OFF2 = 8388608;    // 2*16384*256
constexpr size_t OFF3 = 10485760;   // OFF2 + 2*4096*256
constexpr size_t WS_FLOATS = 11010048;  // OFF3 + 2*1024*256

__device__ inline int box_level(const float* __restrict__ boxes, int m,
                                float& bx0, float& by0, float& bx1, float& by1)
{
    bx0 = boxes[m*4+0]; by0 = boxes[m*4+1];
    bx1 = boxes[m*4+2]; by1 = boxes[m*4+3];
    const float size = sqrtf((bx1-bx0)*(by1-by0));
    float lf = floorf(4.0f + log2f(size/224.0f + 2.220446049250313e-16f));
    lf = fminf(fmaxf(lf, 2.0f), 5.0f);
    return (int)lf - 2;             // 0..3
}

// ---- dense tiled transpose NCHW -> NHWC for levels 1..3 ----
// block: 64 channels x 64 flat px; flat grid over {lvl1:2048, lvl2:512, lvl3:128}
__global__ __launch_bounds__(256) void transpose_kernel(
    const float* __restrict__ f1, const float* __restrict__ f2,
    const float* __restrict__ f3, float* __restrict__ ws)
{
    const int id = blockIdx.x;
    const float* src; size_t offs; int HWsq, rem, tshift;
    if (id < 2048)      { src = f1; offs = OFF1; HWsq = 16384; rem = id;        tshift = 8; }
    else if (id < 2560) { src = f2; offs = OFF2; HWsq = 4096;  rem = id - 2048; tshift = 6; }
    else                { src = f3; offs = OFF3; HWsq = 1024;  rem = id - 2560; tshift = 4; }
    const int tile = rem & ((1 << tshift) - 1);
    const int cg   = (rem >> tshift) & 3;
    const int b    = rem >> (tshift + 2);
    const int px0  = tile << 6;

    __shared__ float tl[64 * 65];
    const int t = threadIdx.x, w = t >> 6, lane = t & 63;

    const float* s = src + (size_t)(b*CTOT + cg*64) * HWsq + px0;
    #pragma unroll
    for (int r = 0; r < 16; ++r) {
        const int ch = r*4 + w;
        tl[ch*65 + lane] = s[(size_t)ch * HWsq + lane];
    }
    __syncthreads();
    float* d = ws + offs + ((size_t)b * HWsq + px0) * CTOT + cg*64;
    #pragma unroll
    for (int r = 0; r < 16; ++r) {
        const int p = r*4 + w;
        d[(size_t)p * CTOT + lane] = tl[lane*65 + p];
    }
}

// ---- pool pass for L1-3 boxes: taps from NHWC ws, lanes over channels ----
__global__ __launch_bounds__(256) void pool_nhwc(
    const float* __restrict__ boxes, const int* __restrict__ bidx,
    const float* __restrict__ ws, float* __restrict__ out)
{
    const int m  = blockIdx.x;
    const int bb = blockIdx.y;          // bins [28bb, 28bb+28)
    float bx0, by0, bx1, by1;
    const int L = box_level(boxes, m, bx0, by0, bx1, by1);
    if (L == 0) return;
    const int HW = 256 >> L;
    const float scale = (L==1) ? 0.125f : (L==2) ? 0.0625f : 0.03125f;
    const size_t offs = (L==1) ? OFF1 : (L==2) ? OFF2 : OFF3;
    const int b = bidx[m];

    __shared__ int4  s_tab[2][NS];      // absolute {lo, hi, wl, wh}
    __shared__ float obuf[28 * 257];

    const int t = threadIdx.x, wave = t >> 6, lane = t & 63;
    if (t < 2*NS) {
        const int axis = t / NS, s = t % NS;
        const float c0 = (axis ? by0 : bx0) * scale - 0.5f;
        const float c1 = (axis ? by1 : bx1) * scale - 0.5f;
        const float binw = (c1 - c0) * (1.0f/OUTD);
        const float g = (float)(s >> 1) + ((s & 1) ? 0.75f : 0.25f);
        const float p = c0 + g * binw;
        const bool valid = (p > -1.0f) && (p < (float)HW);
        const float pc = fminf(fmaxf(p, 0.0f), (float)(HW - 1));
        const int lo = (int)floorf(pc);
        const int hi = min(lo + 1, HW - 1);
        const float l = pc - (float)lo;
        int4 e; e.x = lo; e.y = hi;
        e.z = __float_as_int(valid ? (1.0f - l) : 0.0f);
        e.w = __float_as_int(valid ? l : 0.0f);
        s_tab[axis][s] = e;
    }
    __syncthreads();

    const float* mbase = ws + offs + (size_t)b * HW * HW * CTOT;
    const int rowstr = HW * CTOT;

    for (int lb = 7*wave; lb < 7*wave + 7; ++lb) {
        const int bin = 28*bb + lb;
        const int ph = bin / OUTD, pw = bin - ph*OUTD;
        const int4 ty0 = s_tab[1][2*ph], ty1 = s_tab[1][2*ph+1];
        const int4 tx0 = s_tab[0][2*pw], tx1 = s_tab[0][2*pw+1];
        int ro[4]; float wy[4];
        ro[0]=ty0.x*rowstr; wy[0]=__int_as_float(ty0.z);
        ro[1]=ty0.y*rowstr; wy[1]=__int_as_float(ty0.w);
        ro[2]=ty1.x*rowstr; wy[2]=__int_as_float(ty1.z);
        ro[3]=ty1.y*rowstr; wy[3]=__int_as_float(ty1.w);
        int co[4]; float wx[4];
        co[0]=tx0.x*CTOT; wx[0]=__int_as_float(tx0.z);
        co[1]=tx0.y*CTOT; wx[1]=__int_as_float(tx0.w);
        co[2]=tx1.x*CTOT; wx[2]=__int_as_float(tx1.z);
        co[3]=tx1.y*CTOT; wx[3]=__int_as_float(tx1.w);

        float4 v[16]; float wt[16];
        #pragma unroll
        for (int k = 0; k < 16; ++k) {
            const float* p = mbase + (size_t)(ro[k>>2] + co[k&3]);
            v[k] = ((const float4*)p)[lane];
            wt[k] = wy[k>>2] * wx[k&3];
        }
        float4 a0, a1, a2, a3;
        a0.x=a0.y=a0.z=a0.w=0.f; a1=a0; a2=a0; a3=a0;
        #pragma unroll
        for (int k = 0; k < 16; k += 4) {
            a0.x=fmaf(wt[k],v[k].x,a0.x);   a0.y=fmaf(wt[k],v[k].y,a0.y);
            a0.z=fmaf(wt[k],v[k].z,a0.z);   a0.w=fmaf(wt[k],v[k].w,a0.w);
            a1.x=fmaf(wt[k+1],v[k+1].x,a1.x); a1.y=fmaf(wt[k+1],v[k+1].y,a1.y);
            a1.z=fmaf(wt[k+1],v[k+1].z,a1.z); a1.w=fmaf(wt[k+1],v[k+1].w,a1.w);
            a2.x=fmaf(wt[k+2],v[k+2].x,a2.x); a2.y=fmaf(wt[k+2],v[k+2].y,a2.y);
            a2.z=fmaf(wt[k+2],v[k+2].z,a2.z); a2.w=fmaf(wt[k+2],v[k+2].w,a2.w);
            a3.x=fmaf(wt[k+3],v[k+3].x,a3.x); a3.y=fmaf(wt[k+3],v[k+3].y,a3.y);
            a3.z=fmaf(wt[k+3],v[k+3].z,a3.z); a3.w=fmaf(wt[k+3],v[k+3].w,a3.w);
        }
        a0.x += a1.x + a2.x + a3.x;  a0.y += a1.y + a2.y + a3.y;
        a0.z += a1.z + a2.z + a3.z;  a0.w += a1.w + a2.w + a3.w;
        float* ob = obuf + lb*257;
        ob[4*lane+0] = a0.x*0.25f; ob[4*lane+1] = a0.y*0.25f;
        ob[4*lane+2] = a0.z*0.25f; ob[4*lane+3] = a0.w*0.25f;
    }
    __syncthreads();

    // obuf [28][256] -> out [c][bin]: bin-contiguous stores
    for (int s = t; s < 28*CTOT; s += 256) {
        const int c = s / 28, bp = s - 28*c;
        out[((size_t)(m*CTOT + c))*NBIN + 28*bb + bp] = obuf[bp*257 + c];
    }
}

// ---- direct gather (R2-proven); only_l0=1 -> handle only level-0 boxes ----
__global__ __launch_bounds__(256) void roi_pool_direct(
    const float* __restrict__ f0, const float* __restrict__ f1,
    const float* __restrict__ f2, const float* __restrict__ f3,
    const float* __restrict__ boxes, const int* __restrict__ bidx,
    float* __restrict__ out, int only_l0)
{
    const int m  = blockIdx.x;
    const int cg = blockIdx.y;
    float bx0, by0, bx1, by1;
    const int L = box_level(boxes, m, bx0, by0, bx1, by1);
    if (only_l0 && L != 0) return;
    const float scale = (L==0)?0.25f:(L==1)?0.125f:(L==2)?0.0625f:0.03125f;
    const int HW = 256 >> L;
    const float* feat = (L==0)?f0:(L==1)?f1:(L==2)?f2:f3;
    const int b = bidx[m];

    __shared__ int4 s_tab[2][NS];
    const int t = threadIdx.x;
    if (t < 2*NS) {
        const int axis = t / NS, s = t % NS;
        const float c0 = (axis ? by0 : bx0) * scale - 0.5f;
        const float c1 = (axis ? by1 : bx1) * scale - 0.5f;
        const float binw = (c1 - c0) * (1.0f/OUTD);
        const float g = (float)(s >> 1) + ((s & 1) ? 0.75f : 0.25f);
        const float p = c0 + g * binw;
        const bool valid = (p > -1.0f) && (p < (float)HW);
        const float pc = fminf(fmaxf(p, 0.0f), (float)(HW - 1));
        const int lo = (int)floorf(pc);
        const int hi = min(lo + 1, HW - 1);
        const float l = pc - (float)lo;
        int4 e; e.x = lo; e.y = hi;
        e.z = __float_as_int(valid ? (1.0f - l) : 0.0f);
        e.w = __float_as_int(valid ? l : 0.0f);
        s_tab[axis][s] = e;
    }
    __syncthreads();

    const int W = HW;
    const size_t cs = (size_t)HW*HW;
    const float* gbase = feat + (size_t)(b*CTOT + cg*32)*cs;
    for (int i = t; i < 16*NBIN; i += 256) {
        const int cl = i / NBIN, bin = i - cl*NBIN;
        const int ph = bin / OUTD, pw = bin - ph*OUTD;
        const int4 ty0 = s_tab[1][2*ph], ty1 = s_tab[1][2*ph+1];
        const int4 tx0 = s_tab[0][2*pw], tx1 = s_tab[0][2*pw+1];
        int rs[4]; float wy[4];
        rs[0]=ty0.x*W; wy[0]=__int_as_float(ty0.z);
        rs[1]=ty0.y*W; wy[1]=__int_as_float(ty0.w);
        rs[2]=ty1.x*W; wy[2]=__int_as_float(ty1.z);
        rs[3]=ty1.y*W; wy[3]=__int_as_float(ty1.w);
        int cx[4]; float wx[4];
        cx[0]=tx0.x; wx[0]=__int_as_float(tx0.z);
        cx[1]=tx0.y; wx[1]=__int_as_float(tx0.w);
        cx[2]=tx1.x; wx[2]=__int_as_float(tx1.z);
        cx[3]=tx1.y; wx[3]=__int_as_float(tx1.w);
        const float* b0 = gbase + (size_t)cl*cs;
        const float* b1 = b0 + (size_t)16*cs;
        float v0[16], v1[16], w[16];
        #pragma unroll
        for (int k = 0; k < 16; ++k) {
            const int off = rs[k>>2] + cx[k&3];
            v0[k] = b0[off]; v1[k] = b1[off];
            w[k] = wy[k>>2]*wx[k&3];
        }
        float A0=0.f, A1=0.f;
        #pragma unroll
        for (int k = 0; k < 16; ++k) { A0 += w[k]*v0[k]; A1 += w[k]*v1[k]; }
        const size_t ob = ((size_t)m*CTOT + cg*32 + cl)*NBIN + bin;
        out[ob] = A0*0.25f;
        out[ob + (size_t)16*NBIN] = A1*0.25f;
    }
}

extern "C" void kernel_launch(void* const* d_in, const int* in_sizes, int n_in,
                              void* d_out, int out_size, void* d_ws, size_t ws_size,
                              hipStream_t stream) {
    const float* f0    = (const float*)d_in[0];
    const float* f1    = (const float*)d_in[1];
    const float* f2    = (const float*)d_in[2];
    const float* f3    = (const float*)d_in[3];
    const float* boxes = (const float*)d_in[4];
    const int*   bidx  = (const int*)d_in[5];
    float* out = (float*)d_out;
    float* ws  = (float*)d_ws;

    const int M = in_sizes[5];
    if (ws_size >= WS_FLOATS * sizeof(float)) {
        transpose_kernel<<<2688, 256, 0, stream>>>(f1, f2, f3, ws);
        pool_nhwc<<<dim3(M, 7), 256, 0, stream>>>(boxes, bidx, ws, out);
        roi_pool_direct<<<dim3(M, 8), 256, 0, stream>>>(f0,f1,f2,f3,boxes,bidx,out,1);
    } else {
        roi_pool_direct<<<dim3(M, 8), 256, 0, stream>>>(f0,f1,f2,f3,boxes,bidx,out,0);
    }
}

// Round 6
// 89.822 us; speedup vs baseline: 6.8787x; 1.8499x over previous
//
#include <hip/hip_runtime.h>
#include <cmath>

// ROIAlignV2 multi-level FPN pooler. fp32 in/out.
// R6: dense NCHW->NHWC(bf16) transpose of ALL levels + unified NHWC pool
// (lanes over channels: every tap is one 512B contiguous wave-load).
constexpr int OUTD = 14;
constexpr int NBIN = OUTD * OUTD;   // 196
constexpr int NS   = 28;            // samples per axis
constexpr int CTOT = 256;           // channels

// bf16 ws offsets (ushort elements): lvl0 [2][65536][256], lvl1 [2][16384][256],
// lvl2 [2][4096][256], lvl3 [2][1024][256]
constexpr size_t OFF0 = 0;
constexpr size_t OFF1 = 33554432;        // 2*65536*256
constexpr size_t OFF2 = 41943040;        // OFF1 + 2*16384*256
constexpr size_t OFF3 = 44040192;        // OFF2 + 2*4096*256
constexpr size_t WS_USHORT = 44564480;   // OFF3 + 2*1024*256 (89.1 MB)

__device__ inline int box_level(const float* __restrict__ boxes, int m,
                                float& bx0, float& by0, float& bx1, float& by1)
{
    bx0 = boxes[m*4+0]; by0 = boxes[m*4+1];
    bx1 = boxes[m*4+2]; by1 = boxes[m*4+3];
    const float size = sqrtf((bx1-bx0)*(by1-by0));
    float lf = floorf(4.0f + log2f(size/224.0f + 2.220446049250313e-16f));
    lf = fminf(fmaxf(lf, 2.0f), 5.0f);
    return (int)lf - 2;             // 0..3
}

__device__ inline float b2f(unsigned short u) {
    return __uint_as_float(((unsigned int)u) << 16);
}

// ---- Pass T: dense tiled transpose NCHW fp32 -> NHWC bf16, all levels ----
// block: 64 channels x 64 flat px. grid: f0:8192, f1:2048, f2:512, f3:128
__global__ __launch_bounds__(256) void transpose_kernel(
    const float* __restrict__ f0, const float* __restrict__ f1,
    const float* __restrict__ f2, const float* __restrict__ f3,
    unsigned short* __restrict__ ws)
{
    const int id = blockIdx.x;
    const float* src; size_t offs; int HWsq, rem, tshift;
    if (id < 8192)       { src = f0; offs = OFF0; HWsq = 65536; rem = id;         tshift = 10; }
    else if (id < 10240) { src = f1; offs = OFF1; HWsq = 16384; rem = id - 8192;  tshift = 8; }
    else if (id < 10752) { src = f2; offs = OFF2; HWsq = 4096;  rem = id - 10240; tshift = 6; }
    else                 { src = f3; offs = OFF3; HWsq = 1024;  rem = id - 10752; tshift = 4; }
    const int tile = rem & ((1 << tshift) - 1);
    const int cg   = (rem >> tshift) & 3;
    const int b    = rem >> (tshift + 2);
    const int px0  = tile << 6;

    __shared__ float tl[64 * 65];
    const int t = threadIdx.x, w = t >> 6, lane = t & 63;

    const float* s = src + (size_t)(b*CTOT + cg*64) * HWsq + px0;
    #pragma unroll
    for (int r = 0; r < 16; ++r) {
        const int ch = r*4 + w;
        tl[ch*65 + lane] = s[(size_t)ch * HWsq + lane];
    }
    __syncthreads();
    unsigned short* d = ws + offs + ((size_t)b * HWsq + px0) * CTOT + cg*64;
    #pragma unroll
    for (int r = 0; r < 16; ++r) {
        const int p = r*4 + w;
        unsigned int u = __float_as_uint(tl[lane*65 + p]);
        u = (u + 0x7FFFu + ((u >> 16) & 1u)) >> 16;     // RTNE
        d[(size_t)p * CTOT + lane] = (unsigned short)u;
    }
}

// ---- Pass P: unified pool, taps from NHWC bf16 ws, lanes over channels ----
__global__ __launch_bounds__(256) void pool_nhwc(
    const float* __restrict__ boxes, const int* __restrict__ bidx,
    const unsigned short* __restrict__ ws, float* __restrict__ out)
{
    const int m  = blockIdx.x;
    const int bb = blockIdx.y;          // bins [28bb, 28bb+28)
    float bx0, by0, bx1, by1;
    const int L = box_level(boxes, m, bx0, by0, bx1, by1);
    const int HW = 256 >> L;
    const float scale = (L==0) ? 0.25f : (L==1) ? 0.125f : (L==2) ? 0.0625f : 0.03125f;
    const size_t offs = (L==0) ? OFF0 : (L==1) ? OFF1 : (L==2) ? OFF2 : OFF3;
    const int b = bidx[m];

    __shared__ int4  s_tab[2][NS];      // absolute {lo, hi, wl, wh}
    __shared__ float obuf[28 * 257];

    const int t = threadIdx.x, wave = t >> 6, lane = t & 63;
    if (t < 2*NS) {
        const int axis = t / NS, s = t % NS;
        const float c0 = (axis ? by0 : bx0) * scale - 0.5f;
        const float c1 = (axis ? by1 : bx1) * scale - 0.5f;
        const float binw = (c1 - c0) * (1.0f/OUTD);
        const float g = (float)(s >> 1) + ((s & 1) ? 0.75f : 0.25f);
        const float p = c0 + g * binw;
        const bool valid = (p > -1.0f) && (p < (float)HW);
        const float pc = fminf(fmaxf(p, 0.0f), (float)(HW - 1));
        const int lo = (int)floorf(pc);
        const int hi = min(lo + 1, HW - 1);
        const float l = pc - (float)lo;
        int4 e; e.x = lo; e.y = hi;
        e.z = __float_as_int(valid ? (1.0f - l) : 0.0f);
        e.w = __float_as_int(valid ? l : 0.0f);
        s_tab[axis][s] = e;
    }
    __syncthreads();

    const unsigned short* mbase = ws + offs + (size_t)b * HW * HW * CTOT;
    const int rowstr = HW * CTOT;

    for (int lb = 7*wave; lb < 7*wave + 7; ++lb) {
        const int bin = 28*bb + lb;
        const int ph = bin / OUTD, pw = bin - ph*OUTD;
        const int4 ty0 = s_tab[1][2*ph], ty1 = s_tab[1][2*ph+1];
        const int4 tx0 = s_tab[0][2*pw], tx1 = s_tab[0][2*pw+1];
        int ro[4]; float wy[4];
        ro[0]=ty0.x*rowstr; wy[0]=__int_as_float(ty0.z);
        ro[1]=ty0.y*rowstr; wy[1]=__int_as_float(ty0.w);
        ro[2]=ty1.x*rowstr; wy[2]=__int_as_float(ty1.z);
        ro[3]=ty1.y*rowstr; wy[3]=__int_as_float(ty1.w);
        int co[4]; float wx[4];
        co[0]=tx0.x*CTOT; wx[0]=__int_as_float(tx0.z);
        co[1]=tx0.y*CTOT; wx[1]=__int_as_float(tx0.w);
        co[2]=tx1.x*CTOT; wx[2]=__int_as_float(tx1.z);
        co[3]=tx1.y*CTOT; wx[3]=__int_as_float(tx1.w);

        ushort4 v[16]; float wt[16];
        #pragma unroll
        for (int k = 0; k < 16; ++k) {
            const unsigned short* p = mbase + (size_t)(ro[k>>2] + co[k&3]) + 4*lane;
            v[k] = *(const ushort4*)p;
            wt[k] = wy[k>>2] * wx[k&3];
        }
        float4 a0, a1, a2, a3;
        a0.x=a0.y=a0.z=a0.w=0.f; a1=a0; a2=a0; a3=a0;
        #pragma unroll
        for (int k = 0; k < 16; k += 4) {
            a0.x=fmaf(wt[k],  b2f(v[k].x),  a0.x); a0.y=fmaf(wt[k],  b2f(v[k].y),  a0.y);
            a0.z=fmaf(wt[k],  b2f(v[k].z),  a0.z); a0.w=fmaf(wt[k],  b2f(v[k].w),  a0.w);
            a1.x=fmaf(wt[k+1],b2f(v[k+1].x),a1.x); a1.y=fmaf(wt[k+1],b2f(v[k+1].y),a1.y);
            a1.z=fmaf(wt[k+1],b2f(v[k+1].z),a1.z); a1.w=fmaf(wt[k+1],b2f(v[k+1].w),a1.w);
            a2.x=fmaf(wt[k+2],b2f(v[k+2].x),a2.x); a2.y=fmaf(wt[k+2],b2f(v[k+2].y),a2.y);
            a2.z=fmaf(wt[k+2],b2f(v[k+2].z),a2.z); a2.w=fmaf(wt[k+2],b2f(v[k+2].w),a2.w);
            a3.x=fmaf(wt[k+3],b2f(v[k+3].x),a3.x); a3.y=fmaf(wt[k+3],b2f(v[k+3].y),a3.y);
            a3.z=fmaf(wt[k+3],b2f(v[k+3].z),a3.z); a3.w=fmaf(wt[k+3],b2f(v[k+3].w),a3.w);
        }
        a0.x += a1.x + a2.x + a3.x;  a0.y += a1.y + a2.y + a3.y;
        a0.z += a1.z + a2.z + a3.z;  a0.w += a1.w + a2.w + a3.w;
        float* ob = obuf + lb*257;
        ob[4*lane+0] = a0.x*0.25f; ob[4*lane+1] = a0.y*0.25f;
        ob[4*lane+2] = a0.z*0.25f; ob[4*lane+3] = a0.w*0.25f;
    }
    __syncthreads();

    // obuf [28][256] -> out [c][bin]: bin-contiguous stores
    for (int s = t; s < 28*CTOT; s += 256) {
        const int c = s / 28, bp = s - 28*c;
        out[((size_t)(m*CTOT + c))*NBIN + 28*bb + bp] = obuf[bp*257 + c];
    }
}

// ---- fallback: direct gather (R2-proven), all boxes ----
__global__ __launch_bounds__(256) void roi_pool_direct(
    const float* __restrict__ f0, const float* __restrict__ f1,
    const float* __restrict__ f2, const float* __restrict__ f3,
    const float* __restrict__ boxes, const int* __restrict__ bidx,
    float* __restrict__ out)
{
    const int m  = blockIdx.x;
    const int cg = blockIdx.y;
    float bx0, by0, bx1, by1;
    const int L = box_level(boxes, m, bx0, by0, bx1, by1);
    const float scale = (L==0)?0.25f:(L==1)?0.125f:(L==2)?0.0625f:0.03125f;
    const int HW = 256 >> L;
    const float* feat = (L==0)?f0:(L==1)?f1:(L==2)?f2:f3;
    const int b = bidx[m];

    __shared__ int4 s_tab[2][NS];
    const int t = threadIdx.x;
    if (t < 2*NS) {
        const int axis = t / NS, s = t % NS;
        const float c0 = (axis ? by0 : bx0) * scale - 0.5f;
        const float c1 = (axis ? by1 : bx1) * scale - 0.5f;
        const float binw = (c1 - c0) * (1.0f/OUTD);
        const float g = (float)(s >> 1) + ((s & 1) ? 0.75f : 0.25f);
        const float p = c0 + g * binw;
        const bool valid = (p > -1.0f) && (p < (float)HW);
        const float pc = fminf(fmaxf(p, 0.0f), (float)(HW - 1));
        const int lo = (int)floorf(pc);
        const int hi = min(lo + 1, HW - 1);
        const float l = pc - (float)lo;
        int4 e; e.x = lo; e.y = hi;
        e.z = __float_as_int(valid ? (1.0f - l) : 0.0f);
        e.w = __float_as_int(valid ? l : 0.0f);
        s_tab[axis][s] = e;
    }
    __syncthreads();

    const int W = HW;
    const size_t cs = (size_t)HW*HW;
    const float* gbase = feat + (size_t)(b*CTOT + cg*32)*cs;
    for (int i = t; i < 16*NBIN; i += 256) {
        const int cl = i / NBIN, bin = i - cl*NBIN;
        const int ph = bin / OUTD, pw = bin - ph*OUTD;
        const int4 ty0 = s_tab[1][2*ph], ty1 = s_tab[1][2*ph+1];
        const int4 tx0 = s_tab[0][2*pw], tx1 = s_tab[0][2*pw+1];
        int rs[4]; float wy[4];
        rs[0]=ty0.x*W; wy[0]=__int_as_float(ty0.z);
        rs[1]=ty0.y*W; wy[1]=__int_as_float(ty0.w);
        rs[2]=ty1.x*W; wy[2]=__int_as_float(ty1.z);
        rs[3]=ty1.y*W; wy[3]=__int_as_float(ty1.w);
        int cx[4]; float wx[4];
        cx[0]=tx0.x; wx[0]=__int_as_float(tx0.z);
        cx[1]=tx0.y; wx[1]=__int_as_float(tx0.w);
        cx[2]=tx1.x; wx[2]=__int_as_float(tx1.z);
        cx[3]=tx1.y; wx[3]=__int_as_float(tx1.w);
        const float* b0 = gbase + (size_t)cl*cs;
        const float* b1 = b0 + (size_t)16*cs;
        float v0[16], v1[16], w[16];
        #pragma unroll
        for (int k = 0; k < 16; ++k) {
            const int off = rs[k>>2] + cx[k&3];
            v0[k] = b0[off]; v1[k] = b1[off];
            w[k] = wy[k>>2]*wx[k&3];
        }
        float A0=0.f, A1=0.f;
        #pragma unroll
        for (int k = 0; k < 16; ++k) { A0 += w[k]*v0[k]; A1 += w[k]*v1[k]; }
        const size_t ob = ((size_t)m*CTOT + cg*32 + cl)*NBIN + bin;
        out[ob] = A0*0.25f;
        out[ob + (size_t)16*NBIN] = A1*0.25f;
    }
}

extern "C" void kernel_launch(void* const* d_in, const int* in_sizes, int n_in,
                              void* d_out, int out_size, void* d_ws, size_t ws_size,
                              hipStream_t stream) {
    const float* f0    = (const float*)d_in[0];
    const float* f1    = (const float*)d_in[1];
    const float* f2    = (const float*)d_in[2];
    const float* f3    = (const float*)d_in[3];
    const float* boxes = (const float*)d_in[4];
    const int*   bidx  = (const int*)d_in[5];
    float* out = (float*)d_out;

    const int M = in_sizes[5];
    if (ws_size >= WS_USHORT * sizeof(unsigned short)) {
        unsigned short* ws = (unsigned short*)d_ws;
        transpose_kernel<<<10880, 256, 0, stream>>>(f0, f1, f2, f3, ws);
        pool_nhwc<<<dim3(M, 7), 256, 0, stream>>>(boxes, bidx, ws, out);
    } else {
        roi_pool_direct<<<dim3(M, 8), 256, 0, stream>>>(f0,f1,f2,f3,boxes,bidx,out);
    }
}

// Round 7
// 85.980 us; speedup vs baseline: 7.1860x; 1.0447x over previous
//
#include <hip/hip_runtime.h>
#include <cmath>

// ROIAlignV2 multi-level FPN pooler. fp32 in/out.
// R7: demand-masked dense NCHW->NHWC(bf16) transpose (only tiles touched by
// some box window) + unified NHWC pool (512B contiguous tap loads).
constexpr int OUTD = 14;
constexpr int NBIN = OUTD * OUTD;   // 196
constexpr int NS   = 28;            // samples per axis
constexpr int CTOT = 256;           // channels

// bf16 ws offsets (ushort elements)
constexpr size_t OFF0 = 0;
constexpr size_t OFF1 = 33554432;        // 2*65536*256
constexpr size_t OFF2 = 41943040;        // OFF1 + 2*16384*256
constexpr size_t OFF3 = 44040192;        // OFF2 + 2*4096*256
constexpr size_t WS_USHORT = 44564480;   // OFF3 + 2*1024*256 (89.1 MB)
// tile flags (bytes), appended after bf16 region
constexpr size_t FLAG_BYTE_OFF = WS_USHORT * 2;
constexpr int F0 = 0, F1 = 2048, F2 = 2560, F3 = 2688;   // per-level offsets
constexpr int FLAG_BYTES = 2720;
constexpr size_t WS_NEED = FLAG_BYTE_OFF + FLAG_BYTES;

__device__ inline int box_level(const float* __restrict__ boxes, int m,
                                float& bx0, float& by0, float& bx1, float& by1)
{
    bx0 = boxes[m*4+0]; by0 = boxes[m*4+1];
    bx1 = boxes[m*4+2]; by1 = boxes[m*4+3];
    const float size = sqrtf((bx1-bx0)*(by1-by0));
    float lf = floorf(4.0f + log2f(size/224.0f + 2.220446049250313e-16f));
    lf = fminf(fmaxf(lf, 2.0f), 5.0f);
    return (int)lf - 2;             // 0..3
}

// touched coordinate range [lo, hi] on one axis (same math as pool taps)
__device__ inline void axis_window(float c0, float c1, int HW, int& lo, int& hi)
{
    const float binw = (c1 - c0) * (1.0f/OUTD);
    const float HWm1 = (float)(HW-1);
    const float pL = fminf(fmaxf(c0 + 0.25f*binw, 0.f), HWm1);   // sample 0
    const float pH = fminf(fmaxf(c0 + 13.75f*binw, 0.f), HWm1);  // sample 27
    lo = (int)floorf(pL);
    hi = min((int)floorf(pH) + 1, HW - 1);
}

__device__ inline float b2f(unsigned short u) {
    return __uint_as_float(((unsigned int)u) << 16);
}

// ---- Pass M: zero + mark touched tiles (single block) ----
__global__ __launch_bounds__(256) void mark_kernel(
    const float* __restrict__ boxes, const int* __restrict__ bidx,
    unsigned char* __restrict__ flags, int M)
{
    const int t = threadIdx.x;
    for (int i = t; i < FLAG_BYTES; i += 256) flags[i] = 0;
    __syncthreads();
    for (int m = t; m < M; m += 256) {
        float bx0, by0, bx1, by1;
        const int L = box_level(boxes, m, bx0, by0, bx1, by1);
        const int HW = 256 >> L;
        const float scale = (L==0)?0.25f:(L==1)?0.125f:(L==2)?0.0625f:0.03125f;
        const int foff = (L==0)?F0:(L==1)?F1:(L==2)?F2:F3;
        const int ntiles = (HW*HW) >> 6;
        const int b = bidx[m];
        int xlo, xhi, ylo, yhi;
        axis_window(bx0*scale - 0.5f, bx1*scale - 0.5f, HW, xlo, xhi);
        axis_window(by0*scale - 0.5f, by1*scale - 0.5f, HW, ylo, yhi);
        unsigned char* f = flags + foff + b*ntiles;
        for (int y = ylo; y <= yhi; ++y) {
            const int t0 = (y*HW + xlo) >> 6;
            const int t1 = (y*HW + xhi) >> 6;
            for (int ti = t0; ti <= t1; ++ti) f[ti] = 1;
        }
    }
}

// ---- Pass T: masked tiled transpose NCHW fp32 -> NHWC bf16 ----
// block: 64 channels x 64 flat px. grid: f0:8192, f1:2048, f2:512, f3:128
__global__ __launch_bounds__(256) void transpose_kernel(
    const float* __restrict__ f0, const float* __restrict__ f1,
    const float* __restrict__ f2, const float* __restrict__ f3,
    unsigned short* __restrict__ ws, const unsigned char* __restrict__ flags)
{
    const int id = blockIdx.x;
    const float* src; size_t offs; int HWsq, rem, tshift, foff;
    if (id < 8192)       { src = f0; offs = OFF0; HWsq = 65536; rem = id;         tshift = 10; foff = F0; }
    else if (id < 10240) { src = f1; offs = OFF1; HWsq = 16384; rem = id - 8192;  tshift = 8;  foff = F1; }
    else if (id < 10752) { src = f2; offs = OFF2; HWsq = 4096;  rem = id - 10240; tshift = 6;  foff = F2; }
    else                 { src = f3; offs = OFF3; HWsq = 1024;  rem = id - 10752; tshift = 4;  foff = F3; }
    const int tile = rem & ((1 << tshift) - 1);
    const int cg   = (rem >> tshift) & 3;
    const int b    = rem >> (tshift + 2);
    if (!flags[foff + b*(HWsq >> 6) + tile]) return;
    const int px0  = tile << 6;

    __shared__ float tl[64 * 65];
    const int t = threadIdx.x, w = t >> 6, lane = t & 63;

    const float* s = src + (size_t)(b*CTOT + cg*64) * HWsq + px0;
    #pragma unroll
    for (int r = 0; r < 16; ++r) {
        const int ch = r*4 + w;
        tl[ch*65 + lane] = s[(size_t)ch * HWsq + lane];
    }
    __syncthreads();
    unsigned short* d = ws + offs + ((size_t)b * HWsq + px0) * CTOT + cg*64;
    #pragma unroll
    for (int r = 0; r < 16; ++r) {
        const int p = r*4 + w;
        unsigned int u = __float_as_uint(tl[lane*65 + p]);
        u = (u + 0x7FFFu + ((u >> 16) & 1u)) >> 16;     // RTNE
        d[(size_t)p * CTOT + lane] = (unsigned short)u;
    }
}

// ---- Pass P: unified pool, taps from NHWC bf16 ws, lanes over channels ----
__global__ __launch_bounds__(256) void pool_nhwc(
    const float* __restrict__ boxes, const int* __restrict__ bidx,
    const unsigned short* __restrict__ ws, float* __restrict__ out)
{
    const int m  = blockIdx.x;
    const int bb = blockIdx.y;          // bins [28bb, 28bb+28)
    float bx0, by0, bx1, by1;
    const int L = box_level(boxes, m, bx0, by0, bx1, by1);
    const int HW = 256 >> L;
    const float scale = (L==0) ? 0.25f : (L==1) ? 0.125f : (L==2) ? 0.0625f : 0.03125f;
    const size_t offs = (L==0) ? OFF0 : (L==1) ? OFF1 : (L==2) ? OFF2 : OFF3;
    const int b = bidx[m];

    __shared__ int4  s_tab[2][NS];      // absolute {lo, hi, wl, wh}
    __shared__ float obuf[28 * 257];

    const int t = threadIdx.x, wave = t >> 6, lane = t & 63;
    if (t < 2*NS) {
        const int axis = t / NS, s = t % NS;
        const float c0 = (axis ? by0 : bx0) * scale - 0.5f;
        const float c1 = (axis ? by1 : bx1) * scale - 0.5f;
        const float binw = (c1 - c0) * (1.0f/OUTD);
        const float g = (float)(s >> 1) + ((s & 1) ? 0.75f : 0.25f);
        const float p = c0 + g * binw;
        const bool valid = (p > -1.0f) && (p < (float)HW);
        const float pc = fminf(fmaxf(p, 0.0f), (float)(HW - 1));
        const int lo = (int)floorf(pc);
        const int hi = min(lo + 1, HW - 1);
        const float l = pc - (float)lo;
        int4 e; e.x = lo; e.y = hi;
        e.z = __float_as_int(valid ? (1.0f - l) : 0.0f);
        e.w = __float_as_int(valid ? l : 0.0f);
        s_tab[axis][s] = e;
    }
    __syncthreads();

    const unsigned short* mbase = ws + offs + (size_t)b * HW * HW * CTOT;
    const int rowstr = HW * CTOT;

    for (int lb = 7*wave; lb < 7*wave + 7; ++lb) {
        const int bin = 28*bb + lb;
        const int ph = bin / OUTD, pw = bin - ph*OUTD;
        const int4 ty0 = s_tab[1][2*ph], ty1 = s_tab[1][2*ph+1];
        const int4 tx0 = s_tab[0][2*pw], tx1 = s_tab[0][2*pw+1];
        int ro[4]; float wy[4];
        ro[0]=ty0.x*rowstr; wy[0]=__int_as_float(ty0.z);
        ro[1]=ty0.y*rowstr; wy[1]=__int_as_float(ty0.w);
        ro[2]=ty1.x*rowstr; wy[2]=__int_as_float(ty1.z);
        ro[3]=ty1.y*rowstr; wy[3]=__int_as_float(ty1.w);
        int co[4]; float wx[4];
        co[0]=tx0.x*CTOT; wx[0]=__int_as_float(tx0.z);
        co[1]=tx0.y*CTOT; wx[1]=__int_as_float(tx0.w);
        co[2]=tx1.x*CTOT; wx[2]=__int_as_float(tx1.z);
        co[3]=tx1.y*CTOT; wx[3]=__int_as_float(tx1.w);

        ushort4 v[16]; float wt[16];
        #pragma unroll
        for (int k = 0; k < 16; ++k) {
            const unsigned short* p = mbase + (size_t)(ro[k>>2] + co[k&3]) + 4*lane;
            v[k] = *(const ushort4*)p;
            wt[k] = wy[k>>2] * wx[k&3];
        }
        float4 a0, a1, a2, a3;
        a0.x=a0.y=a0.z=a0.w=0.f; a1=a0; a2=a0; a3=a0;
        #pragma unroll
        for (int k = 0; k < 16; k += 4) {
            a0.x=fmaf(wt[k],  b2f(v[k].x),  a0.x); a0.y=fmaf(wt[k],  b2f(v[k].y),  a0.y);
            a0.z=fmaf(wt[k],  b2f(v[k].z),  a0.z); a0.w=fmaf(wt[k],  b2f(v[k].w),  a0.w);
            a1.x=fmaf(wt[k+1],b2f(v[k+1].x),a1.x); a1.y=fmaf(wt[k+1],b2f(v[k+1].y),a1.y);
            a1.z=fmaf(wt[k+1],b2f(v[k+1].z),a1.z); a1.w=fmaf(wt[k+1],b2f(v[k+1].w),a1.w);
            a2.x=fmaf(wt[k+2],b2f(v[k+2].x),a2.x); a2.y=fmaf(wt[k+2],b2f(v[k+2].y),a2.y);
            a2.z=fmaf(wt[k+2],b2f(v[k+2].z),a2.z); a2.w=fmaf(wt[k+2],b2f(v[k+2].w),a2.w);
            a3.x=fmaf(wt[k+3],b2f(v[k+3].x),a3.x); a3.y=fmaf(wt[k+3],b2f(v[k+3].y),a3.y);
            a3.z=fmaf(wt[k+3],b2f(v[k+3].z),a3.z); a3.w=fmaf(wt[k+3],b2f(v[k+3].w),a3.w);
        }
        a0.x += a1.x + a2.x + a3.x;  a0.y += a1.y + a2.y + a3.y;
        a0.z += a1.z + a2.z + a3.z;  a0.w += a1.w + a2.w + a3.w;
        float* ob = obuf + lb*257;
        ob[4*lane+0] = a0.x*0.25f; ob[4*lane+1] = a0.y*0.25f;
        ob[4*lane+2] = a0.z*0.25f; ob[4*lane+3] = a0.w*0.25f;
    }
    __syncthreads();

    // obuf [28][256] -> out [c][bin]: bin-contiguous stores
    for (int s = t; s < 28*CTOT; s += 256) {
        const int c = s / 28, bp = s - 28*c;
        out[((size_t)(m*CTOT + c))*NBIN + 28*bb + bp] = obuf[bp*257 + c];
    }
}

// ---- fallback: direct gather (R2-proven), all boxes ----
__global__ __launch_bounds__(256) void roi_pool_direct(
    const float* __restrict__ f0, const float* __restrict__ f1,
    const float* __restrict__ f2, const float* __restrict__ f3,
    const float* __restrict__ boxes, const int* __restrict__ bidx,
    float* __restrict__ out)
{
    const int m  = blockIdx.x;
    const int cg = blockIdx.y;
    float bx0, by0, bx1, by1;
    const int L = box_level(boxes, m, bx0, by0, bx1, by1);
    const float scale = (L==0)?0.25f:(L==1)?0.125f:(L==2)?0.0625f:0.03125f;
    const int HW = 256 >> L;
    const float* feat = (L==0)?f0:(L==1)?f1:(L==2)?f2:f3;
    const int b = bidx[m];

    __shared__ int4 s_tab[2][NS];
    const int t = threadIdx.x;
    if (t < 2*NS) {
        const int axis = t / NS, s = t % NS;
        const float c0 = (axis ? by0 : bx0) * scale - 0.5f;
        const float c1 = (axis ? by1 : bx1) * scale - 0.5f;
        const float binw = (c1 - c0) * (1.0f/OUTD);
        const float g = (float)(s >> 1) + ((s & 1) ? 0.75f : 0.25f);
        const float p = c0 + g * binw;
        const bool valid = (p > -1.0f) && (p < (float)HW);
        const float pc = fminf(fmaxf(p, 0.0f), (float)(HW - 1));
        const int lo = (int)floorf(pc);
        const int hi = min(lo + 1, HW - 1);
        const float l = pc - (float)lo;
        int4 e; e.x = lo; e.y = hi;
        e.z = __float_as_int(valid ? (1.0f - l) : 0.0f);
        e.w = __float_as_int(valid ? l : 0.0f);
        s_tab[axis][s] = e;
    }
    __syncthreads();

    const int W = HW;
    const size_t cs = (size_t)HW*HW;
    const float* gbase = feat + (size_t)(b*CTOT + cg*32)*cs;
    for (int i = t; i < 16*NBIN; i += 256) {
        const int cl = i / NBIN, bin = i - cl*NBIN;
        const int ph = bin / OUTD, pw = bin - ph*OUTD;
        const int4 ty0 = s_tab[1][2*ph], ty1 = s_tab[1][2*ph+1];
        const int4 tx0 = s_tab[0][2*pw], tx1 = s_tab[0][2*pw+1];
        int rs[4]; float wy[4];
        rs[0]=ty0.x*W; wy[0]=__int_as_float(ty0.z);
        rs[1]=ty0.y*W; wy[1]=__int_as_float(ty0.w);
        rs[2]=ty1.x*W; wy[2]=__int_as_float(ty1.z);
        rs[3]=ty1.y*W; wy[3]=__int_as_float(ty1.w);
        int cx[4]; float wx[4];
        cx[0]=tx0.x; wx[0]=__int_as_float(tx0.z);
        cx[1]=tx0.y; wx[1]=__int_as_float(tx0.w);
        cx[2]=tx1.x; wx[2]=__int_as_float(tx1.z);
        cx[3]=tx1.y; wx[3]=__int_as_float(tx1.w);
        const float* b0 = gbase + (size_t)cl*cs;
        const float* b1 = b0 + (size_t)16*cs;
        float v0[16], v1[16], w[16];
        #pragma unroll
        for (int k = 0; k < 16; ++k) {
            const int off = rs[k>>2] + cx[k&3];
            v0[k] = b0[off]; v1[k] = b1[off];
            w[k] = wy[k>>2]*wx[k&3];
        }
        float A0=0.f, A1=0.f;
        #pragma unroll
        for (int k = 0; k < 16; ++k) { A0 += w[k]*v0[k]; A1 += w[k]*v1[k]; }
        const size_t ob = ((size_t)m*CTOT + cg*32 + cl)*NBIN + bin;
        out[ob] = A0*0.25f;
        out[ob + (size_t)16*NBIN] = A1*0.25f;
    }
}

extern "C" void kernel_launch(void* const* d_in, const int* in_sizes, int n_in,
                              void* d_out, int out_size, void* d_ws, size_t ws_size,
                              hipStream_t stream) {
    const float* f0    = (const float*)d_in[0];
    const float* f1    = (const float*)d_in[1];
    const float* f2    = (const float*)d_in[2];
    const float* f3    = (const float*)d_in[3];
    const float* boxes = (const float*)d_in[4];
    const int*   bidx  = (const int*)d_in[5];
    float* out = (float*)d_out;

    const int M = in_sizes[5];
    if (ws_size >= WS_NEED) {
        unsigned short* ws = (unsigned short*)d_ws;
        unsigned char* flags = (unsigned char*)d_ws + FLAG_BYTE_OFF;
        mark_kernel<<<1, 256, 0, stream>>>(boxes, bidx, flags, M);
        transpose_kernel<<<10880, 256, 0, stream>>>(f0, f1, f2, f3, ws, flags);
        pool_nhwc<<<dim3(M, 7), 256, 0, stream>>>(boxes, bidx, ws, out);
    } else {
        roi_pool_direct<<<dim3(M, 8), 256, 0, stream>>>(f0,f1,f2,f3,boxes,bidx,out);
    }
}